// Round 2
// baseline (185.079 us; speedup 1.0000x reference)
//
#include <hip/hip_runtime.h>
#include <hip/hip_bf16.h>

// PAM module R8: q/k/v 1x1 projections -> bf16 MFMA attention -> gamma*out + x.
// R7 post-mortem: softmax/S interleave was neutral -> the ~1400cy/tile stall is
// exposed K/V load latency (2GB through L2 @ ~60% BW, V load-use distance 1
// phase, compiler-owned vmcnt). R8: V goes through a double-buffered WAVE-
// PRIVATE LDS landing zone via global_load_lds (zero VGPR cost, 2-half-step
// prefetch distance); ONE explicit counted s_waitcnt vmcnt(16)+sched_barrier
// per half-step guarantees V(t)/K(t+1) landed while keeping the newest 16
// prefetch ops (next V-stage + next K-load) in flight -- never drains to 0.
// V ds_reads issue before FUSED so lgkm latency hides under S-MFMAs. K stays
// register ping-pong (distance 2). red[] overlays the V buffers (union) to
// keep LDS at 66KB -> 2 blocks/CU.
//
// Workspace layouts (bf16, chunk = 64 lanes x 16B = 1KB, frag-major):
//   qf_ws[b][strip32][ni2][kc4][lane]         8MB  (PRE-SCALED by log2e)
//   kt   [b][tile128][mb8][kc4][lane]         8MB
//   vt   [b][tile128][cb*16+wq][l16]{8}       8MB

typedef __bf16 v8bf __attribute__((ext_vector_type(8)));
typedef float  v4f  __attribute__((ext_vector_type(4)));

#define B_ 8
#define C_ 128
#define N_ 4096

static __device__ __forceinline__ unsigned short f2bf_rne(float f) {
    union { float f; unsigned u; } v; v.f = f;
    return (unsigned short)((v.u + 0x7fffu + ((v.u >> 16) & 1u)) >> 16);
}
static __device__ __forceinline__ unsigned fbits(float f) {
    union { float f; unsigned u; } v; v.f = f; return v.u;
}

// ---------------------------------------------------------------------------
// Kernel 1: unchanged from R7 (log2e folded into Q weights).
// ---------------------------------------------------------------------------
__global__ __launch_bounds__(256, 2) void proj_kernel(
    const float* __restrict__ x,
    const float* __restrict__ dw_q, const float* __restrict__ pw_q,
    const float* __restrict__ dw_k, const float* __restrict__ pw_k,
    const float* __restrict__ dw_v, const float* __restrict__ pw_v,
    unsigned short* __restrict__ qf_ws, unsigned short* __restrict__ kt,
    unsigned short* __restrict__ vt)
{
    __shared__ unsigned short xT[128 * 136];  // xT[n][c]
    __shared__ unsigned short Ws[128 * 136];  // W[o][c]; reused as store scratch

    const int bid = blockIdx.x;
    const int bb  = bid & 7;
    const int t   = (bid >> 3) & 31;
    const int pp  = bid >> 8;            // 0:q 1:k 2:v
    const int n0  = t * 128;
    const int tid = threadIdx.x;
    const int w    = tid >> 6;
    const int lane = tid & 63;
    const int quad = lane >> 4;
    const int l16  = lane & 15;

    #pragma unroll
    for (int k = 0; k < 16; ++k) {
        const int idx = tid + k * 256;
        const int c  = idx >> 5;
        const int nq = idx & 31;
        float4 f = *(const float4*)(x + ((size_t)(bb * C_ + c)) * N_ + n0 + nq * 4);
        xT[(nq * 4 + 0) * 136 + c] = f2bf_rne(f.x);
        xT[(nq * 4 + 1) * 136 + c] = f2bf_rne(f.y);
        xT[(nq * 4 + 2) * 136 + c] = f2bf_rne(f.z);
        xT[(nq * 4 + 3) * 136 + c] = f2bf_rne(f.w);
    }
    const float* pw = (pp == 0) ? pw_q : (pp == 1) ? pw_k : pw_v;
    const float* dw = (pp == 0) ? dw_q : (pp == 1) ? dw_k : dw_v;
    const float qs = (pp == 0) ? 1.4426950408889634f : 1.0f;
    #pragma unroll
    for (int k = 0; k < 16; ++k) {
        const int idx = tid + k * 256;
        const int o  = idx >> 5;
        const int c4 = (idx & 31) * 4;
        float4 p4 = *(const float4*)(pw + o * 128 + c4);
        float4 d4 = *(const float4*)(dw + c4);
        unsigned lo = (unsigned)f2bf_rne(p4.x * d4.x * qs) | ((unsigned)f2bf_rne(p4.y * d4.y * qs) << 16);
        unsigned hi = (unsigned)f2bf_rne(p4.z * d4.z * qs) | ((unsigned)f2bf_rne(p4.w * d4.w * qs) << 16);
        *(unsigned long long*)&Ws[o * 136 + c4] =
            (unsigned long long)lo | ((unsigned long long)hi << 32);
    }
    __syncthreads();

    const unsigned short* As = (pp < 2) ? xT : Ws;
    const unsigned short* Bs = (pp < 2) ? Ws : xT;

    v4f acc[2][8];
    #pragma unroll
    for (int i = 0; i < 2; ++i)
        #pragma unroll
        for (int j = 0; j < 8; ++j)
            acc[i][j] = (v4f){0.f, 0.f, 0.f, 0.f};

    #pragma unroll
    for (int kc = 0; kc < 4; ++kc) {
        v8bf av[2];
        #pragma unroll
        for (int i = 0; i < 2; ++i)
            av[i] = *(const v8bf*)&As[(w * 32 + i * 16 + l16) * 136 + kc * 32 + quad * 8];
        #pragma unroll
        for (int cb = 0; cb < 8; ++cb) {
            v8bf bv = *(const v8bf*)&Bs[(cb * 16 + l16) * 136 + kc * 32 + quad * 8];
            acc[0][cb] = __builtin_amdgcn_mfma_f32_16x16x32_bf16(av[0], bv, acc[0][cb], 0, 0, 0);
            acc[1][cb] = __builtin_amdgcn_mfma_f32_16x16x32_bf16(av[1], bv, acc[1][cb], 0, 0, 0);
        }
    }
    __syncthreads();

    unsigned short* sc = Ws;
    #pragma unroll
    for (int mi = 0; mi < 2; ++mi)
        #pragma unroll
        for (int cb = 0; cb < 8; ++cb)
            #pragma unroll
            for (int r = 0; r < 4; ++r)
                sc[(w * 32 + mi * 16 + quad * 4 + r) * 136 + cb * 16 + l16] =
                    f2bf_rne(acc[mi][cb][r]);
    __syncthreads();

    if (pp == 0) {
        unsigned short* dst = qf_ws + ((size_t)(bb * 64 + t * 2)) * 8192;
        #pragma unroll
        for (int p = 0; p < 8; ++p) {
            const int g     = p * 4 + w;
            const int strip = g >> 4, ni = (g >> 2) & 3, kc = g & 3;
            *(uint4*)(dst + ((size_t)g * 64 + lane) * 8) =
                *(const uint4*)&sc[(strip * 64 + ni * 16 + l16) * 136 + kc * 32 + quad * 8];
        }
    } else if (pp == 1) {
        unsigned short* dst = kt + ((size_t)(bb * 32 + t)) * 16384;
        #pragma unroll
        for (int p = 0; p < 8; ++p) {
            const int g  = p * 4 + w;
            const int mb = g >> 2, kc = g & 3;
            *(uint4*)(dst + ((size_t)g * 64 + lane) * 8) =
                *(const uint4*)&sc[(mb * 16 + l16) * 136 + kc * 32 + quad * 8];
        }
    } else {
        unsigned short* dst = vt + ((size_t)(bb * 32 + t)) * 16384;
        #pragma unroll
        for (int p = 0; p < 8; ++p) {
            const int d  = p * 256 + tid;
            const int cb = d >> 8, wq = (d >> 4) & 15, l = d & 15;
            *(uint4*)(dst + (size_t)d * 8) =
                *(const uint4*)&sc[(cb * 16 + l) * 136 + wq * 8];
        }
    }
}

// ---------------------------------------------------------------------------
// Kernel 2: attention. grid 1024 = (b = bid&7, 32-row n-strip = bid>>3).
// 256 thr / 4 waves; wave = m-quarter, full c=128, n=32.
// ---------------------------------------------------------------------------
#define MFMA(A, B, C) __builtin_amdgcn_mfma_f32_16x16x32_bf16(A, B, C, 0, 0, 0)
#define EXP2(X) __builtin_amdgcn_exp2f(X)
#define PKPERM(EH, EL) __builtin_amdgcn_perm(fbits(EH), fbits(EL), 0x07060302)

#define LOADK(KF, TILE) { \
    const unsigned short* kp_ = kbase + (size_t)(TILE) * 16384; \
    _Pragma("unroll") \
    for (int mi_ = 0; mi_ < 2; ++mi_) \
        _Pragma("unroll") \
        for (int kc_ = 0; kc_ < 4; ++kc_) \
            KF[mi_][kc_] = *(const v8bf*)(kp_ + (size_t)((mi_ * 4 + kc_) * 64) * 8); \
}

// Stage V(TILE) for this wave into its private LDS region (8 x global_load_lds,
// 16B/lane, linear dest = base + lane*16 matches the [cb][lane]{8} layout).
#define STAGE_V(TILE, BUF) { \
    const unsigned short* vp_ = vstage + (size_t)(TILE) * 16384; \
    _Pragma("unroll") \
    for (int cb_ = 0; cb_ < 8; ++cb_) \
        __builtin_amdgcn_global_load_lds( \
            (const __attribute__((address_space(1))) void*)(vp_ + cb_ * 2048), \
            (__attribute__((address_space(3))) void*)&sm.v[BUF][w][cb_][0], \
            16, 0, 0); \
}

// ds_read V(t) into regs; issued BEFORE FUSED so lgkm latency hides under S.
#define VLOAD(BUF) { \
    _Pragma("unroll") \
    for (int cb_ = 0; cb_ < 8; ++cb_) \
        vv[cb_] = *(const v8bf*)&sm.v[BUF][w][cb_][lane * 8]; \
}

// Counted wait: everything except the 16 newest vmem ops (next V-stage 8 +
// next K-load 8) has landed => V(t) and K(t+1) are guaranteed resident while
// the prefetch pipeline stays in flight. sched_barrier pins program order.
#define VWAIT { asm volatile("s_waitcnt vmcnt(16)" ::: "memory"); \
                __builtin_amdgcn_sched_barrier(0); }
// Drain LDS reads before overwriting the buffer with the next stage.
#define LDRAIN { asm volatile("s_waitcnt lgkmcnt(0)" ::: "memory"); \
                 __builtin_amdgcn_sched_barrier(0); }

#define MKPF(NI, PK0A, PK0B, PK1A, PK1B) { \
    unsigned sLo_ = (quad < 2) ? PK0A : PK1A; \
    unsigned sHi_ = (quad < 2) ? PK0B : PK1B; \
    union { unsigned u[4]; v8bf v; } pu_; \
    pu_.u[0] = (unsigned)__builtin_amdgcn_ds_bpermute(la, (int)sLo_); \
    pu_.u[1] = (unsigned)__builtin_amdgcn_ds_bpermute(la, (int)sHi_); \
    pu_.u[2] = (unsigned)__builtin_amdgcn_ds_bpermute(lb, (int)sLo_); \
    pu_.u[3] = (unsigned)__builtin_amdgcn_ds_bpermute(lb, (int)sHi_); \
    pf[NI] = pu_.v; \
}

#define SCOMP0(KF, SC) { \
    _Pragma("unroll") \
    for (int mi_ = 0; mi_ < 2; ++mi_) \
        _Pragma("unroll") \
        for (int ni_ = 0; ni_ < 2; ++ni_) { \
            v4f a_ = MFMA(KF[mi_][0], qf[ni_][0], Z4v); \
            _Pragma("unroll") \
            for (int kc_ = 1; kc_ < 4; ++kc_) \
                a_ = MFMA(KF[mi_][kc_], qf[ni_][kc_], a_); \
            SC[mi_][ni_] = a_; \
        } \
}

// softmax(SC_IN) hand-interleaved with the 16 S-MFMAs of the next tile.
#define FUSED(SC_IN, KF, SC_OUT) { \
    float e0_, e1_, e2_, e3_; \
    unsigned pk00a_, pk00b_, pk10a_, pk10b_, pk01a_, pk01b_, pk11a_, pk11b_; \
    SC_OUT[0][0] = MFMA(KF[0][0], qf[0][0], Z4v); \
    SC_OUT[0][1] = MFMA(KF[0][0], qf[1][0], Z4v); \
    e0_ = EXP2(SC_IN[0][0][0]); e1_ = EXP2(SC_IN[0][0][1]); \
    e2_ = EXP2(SC_IN[0][0][2]); e3_ = EXP2(SC_IN[0][0][3]); \
    SC_OUT[0][0] = MFMA(KF[0][1], qf[0][1], SC_OUT[0][0]); \
    SC_OUT[0][1] = MFMA(KF[0][1], qf[1][1], SC_OUT[0][1]); \
    lpart[0] += (e0_ + e1_) + (e2_ + e3_); \
    pk00a_ = PKPERM(e1_, e0_); pk00b_ = PKPERM(e3_, e2_); \
    SC_OUT[0][0] = MFMA(KF[0][2], qf[0][2], SC_OUT[0][0]); \
    SC_OUT[0][1] = MFMA(KF[0][2], qf[1][2], SC_OUT[0][1]); \
    e0_ = EXP2(SC_IN[1][0][0]); e1_ = EXP2(SC_IN[1][0][1]); \
    e2_ = EXP2(SC_IN[1][0][2]); e3_ = EXP2(SC_IN[1][0][3]); \
    SC_OUT[0][0] = MFMA(KF[0][3], qf[0][3], SC_OUT[0][0]); \
    SC_OUT[0][1] = MFMA(KF[0][3], qf[1][3], SC_OUT[0][1]); \
    lpart[0] += (e0_ + e1_) + (e2_ + e3_); \
    pk10a_ = PKPERM(e1_, e0_); pk10b_ = PKPERM(e3_, e2_); \
    SC_OUT[1][0] = MFMA(KF[1][0], qf[0][0], Z4v); \
    SC_OUT[1][1] = MFMA(KF[1][0], qf[1][0], Z4v); \
    MKPF(0, pk00a_, pk00b_, pk10a_, pk10b_) \
    SC_OUT[1][0] = MFMA(KF[1][1], qf[0][1], SC_OUT[1][0]); \
    SC_OUT[1][1] = MFMA(KF[1][1], qf[1][1], SC_OUT[1][1]); \
    e0_ = EXP2(SC_IN[0][1][0]); e1_ = EXP2(SC_IN[0][1][1]); \
    e2_ = EXP2(SC_IN[0][1][2]); e3_ = EXP2(SC_IN[0][1][3]); \
    SC_OUT[1][0] = MFMA(KF[1][2], qf[0][2], SC_OUT[1][0]); \
    SC_OUT[1][1] = MFMA(KF[1][2], qf[1][2], SC_OUT[1][1]); \
    lpart[1] += (e0_ + e1_) + (e2_ + e3_); \
    pk01a_ = PKPERM(e1_, e0_); pk01b_ = PKPERM(e3_, e2_); \
    SC_OUT[1][0] = MFMA(KF[1][3], qf[0][3], SC_OUT[1][0]); \
    SC_OUT[1][1] = MFMA(KF[1][3], qf[1][3], SC_OUT[1][1]); \
    e0_ = EXP2(SC_IN[1][1][0]); e1_ = EXP2(SC_IN[1][1][1]); \
    e2_ = EXP2(SC_IN[1][1][2]); e3_ = EXP2(SC_IN[1][1][3]); \
    lpart[1] += (e0_ + e1_) + (e2_ + e3_); \
    pk11a_ = PKPERM(e1_, e0_); pk11b_ = PKPERM(e3_, e2_); \
    MKPF(1, pk01a_, pk01b_, pk11a_, pk11b_) \
}

#define PVMM { \
    _Pragma("unroll") \
    for (int ni_ = 0; ni_ < 2; ++ni_) \
        _Pragma("unroll") \
        for (int cb_ = 0; cb_ < 8; ++cb_) \
            oacc[cb_][ni_] = MFMA(vv[cb_], pf[ni_], oacc[cb_][ni_]); \
}

__global__ __launch_bounds__(256, 2) void attn_kernel(
    const unsigned short* __restrict__ qf_ws, const unsigned short* __restrict__ kt,
    const unsigned short* __restrict__ vt, const float* __restrict__ x,
    const float* __restrict__ gamma, float* __restrict__ out)
{
    // V landing zone (2 buffers x 4 waves x 8KB, wave-private) overlaid with
    // the O-reduction scratch (used only after the main loop + barrier).
    __shared__ __align__(16) union SMem {
        unsigned short v[2][4][8][512];   // [buf][wave][cb][lane*8] = 64KB
        float red[32 * 132];              // 16.9KB, aliases buf 0
    } sm;
    __shared__ float l_s[4][32];

    const int bid = blockIdx.x;
    const int bb  = bid & 7;
    const int s   = bid >> 3;        // n-strip 0..127 (32 rows each)
    const int n0  = s * 32;
    const int tid = threadIdx.x;
    const int w    = tid >> 6;       // wave = m-quarter owner
    const int lane = tid & 63;
    const int quad = lane >> 4;
    const int l16  = lane & 15;

    // ---- Q fragments (n=32 strip): 32 VGPR, iteration-invariant
    v8bf qf[2][4];
    {
        const unsigned short* qb = qf_ws + ((size_t)(bb * 128 + s)) * 4096;
        #pragma unroll
        for (int ni = 0; ni < 2; ++ni)
            #pragma unroll
            for (int kc = 0; kc < 4; ++kc)
                qf[ni][kc] = *(const v8bf*)(qb + ((size_t)(ni * 4 + kc) * 64 + lane) * 8);
    }

    v4f oacc[8][2];  // [cb][ni] partial O over this wave's 32-m subset
    #pragma unroll
    for (int i = 0; i < 8; ++i)
        #pragma unroll
        for (int j = 0; j < 2; ++j)
            oacc[i][j] = (v4f){0.f, 0.f, 0.f, 0.f};
    float lpart[2] = {0.f, 0.f};
    const v4f Z4v = {0.f, 0.f, 0.f, 0.f};

    const int la = ((((quad & 1) << 1) << 4) + l16) << 2;  // bpermute byte idx
    const int lb = la + 64;

    const unsigned short* kbase  = kt + ((size_t)(bb * 32)) * 16384 + ((size_t)(w * 8) * 64 + lane) * 8;
    const unsigned short* vstage = vt + ((size_t)(bb * 32)) * 16384 + ((size_t)(w * 64 + lane)) * 8;

    v8bf kfA[2][4], kfB[2][4], vv[8];
    v4f sc0[2][2], sc1[2][2];
    v8bf pf[2];

    // Prologue: K(0),K(1) in regs; V(0),V(1) staging into LDS; S(0) computed.
    LOADK(kfA, 0)
    STAGE_V(0, 0)
    LOADK(kfB, 1)
    STAGE_V(1, 1)
    SCOMP0(kfA, sc0)

    for (int it = 0; it < 32; it += 2) {
        LOADK(kfA, (it + 2) & 31)
        VWAIT                         // V(it), K(it+1) landed; V(it+1)/K(it+2) in flight
        VLOAD(0)                      // ds_read V(it); drains under FUSED
        FUSED(sc0, kfB, sc1)          // softmax(it) || S(it+1)
        PVMM                          // PV(it)
        LDRAIN                        // vv reads done -> buf 0 reusable
        STAGE_V((it + 2) & 31, 0)
        LOADK(kfB, (it + 3) & 31)
        VWAIT                         // V(it+1), K(it+2) landed
        VLOAD(1)
        FUSED(sc1, kfA, sc0)          // softmax(it+1) || S(it+2)
        PVMM                          // PV(it+1)
        LDRAIN
        STAGE_V((it + 3) & 31, 1)
    }

    // ---- softmax denominators (per-wave partials over its 32-m subset)
    #pragma unroll
    for (int ni = 0; ni < 2; ++ni) {
        float r = lpart[ni];
        r += __shfl_xor(r, 16);
        r += __shfl_xor(r, 32);
        if (lane < 16) l_s[w][ni * 16 + lane] = r;
    }

    // All waves must be done with sm.v before red (aliased) is written.
    __syncthreads();

    // ---- O reduction across the 4 m-quarter waves
    for (int rw = 0; rw < 4; ++rw) {
        if (w == rw) {
            #pragma unroll
            for (int cb = 0; cb < 8; ++cb)
                #pragma unroll
                for (int ni = 0; ni < 2; ++ni) {
                    float* p = &sm.red[(ni * 16 + l16) * 132 + cb * 16 + quad * 4];
                    if (rw == 0) *(v4f*)p = oacc[cb][ni];
                    else {
                        v4f tv = *(const v4f*)p;
                        tv += oacc[cb][ni];
                        *(v4f*)p = tv;
                    }
                }
        }
        __syncthreads();
    }

    // ---- epilogue: out = gamma * O / l + x  (thread: n = tid&31, c-group = tid>>5)
    const float g = gamma[0];
    const int   n = tid & 31;
    const int  cg = tid >> 5;        // 0..7
    const float li = 1.0f / (((l_s[0][n] + l_s[1][n]) + (l_s[2][n] + l_s[3][n])));
    #pragma unroll
    for (int j = 0; j < 16; ++j) {
        const int c = cg * 16 + j;
        const size_t idx = ((size_t)(bb * C_ + c)) * N_ + n0 + n;
        out[idx] = g * sm.red[n * 132 + c] * li + x[idx];
    }
}

// ---------------------------------------------------------------------------
extern "C" void kernel_launch(void* const* d_in, const int* in_sizes, int n_in,
                              void* d_out, int out_size, void* d_ws, size_t ws_size,
                              hipStream_t stream)
{
    (void)in_sizes; (void)n_in; (void)out_size; (void)ws_size;
    const float* x     = (const float*)d_in[0];
    const float* dw_q  = (const float*)d_in[1];
    const float* pw_q  = (const float*)d_in[2];
    const float* dw_k  = (const float*)d_in[3];
    const float* pw_k  = (const float*)d_in[4];
    const float* dw_v  = (const float*)d_in[5];
    const float* pw_v  = (const float*)d_in[6];
    const float* gamma = (const float*)d_in[7];
    float* out = (float*)d_out;

    unsigned short* qf_ws = (unsigned short*)d_ws;                  // 8 MB
    unsigned short* kt    = qf_ws + (size_t)B_ * N_ * C_;           // 8 MB
    unsigned short* vt    = kt    + (size_t)B_ * N_ * C_;           // 8 MB

    proj_kernel<<<dim3(768), dim3(256), 0, stream>>>(
        x, dw_q, pw_q, dw_k, pw_k, dw_v, pw_v, qf_ws, kt, vt);
    attn_kernel<<<dim3(1024), dim3(256), 0, stream>>>(
        qf_ws, kt, vt, x, gamma, out);
}

// Round 3
// 174.060 us; speedup vs baseline: 1.0633x; 1.0633x over previous
//
#include <hip/hip_runtime.h>
#include <hip/hip_bf16.h>

// PAM module R9: q/k/v 1x1 projections -> bf16 MFMA attention -> gamma*out + x.
// R8 post-mortem: V-through-LDS with counted vmcnt was NULL (even -3.5us) ->
// load latency was already hidden; attn reverted to R7 (best: 96.7us).
// New target: proj_kernel. Total-attn has been a stable 82-87us across rounds
// vs a ~13us proj roofline. Identified pathology: the xT transpose fill writes
// u16 at (4*nq+r)*136+c -> lane bank step (4*136*2/4)%32 = 16 -> 32 lanes on
// 2 banks = 32-way conflict x 64 stores/thread on the CU-shared LDS pipe.
// R9 fix: row stride 160 shorts (20x16B chunks, data in chunks 0..15) + XOR
// swizzle chunk ^= (row>>2)&15 on ALL xT/Ws/sc accesses (SWZ macro). Fill
// becomes ~2-way (free), writeback ~2-way, MFMA reads ~2-4-way; 16B alignment
// preserved for b64/b128 access widths. LDS 80KB -> still 2 blocks/CU.
//
// Workspace layouts (bf16, chunk = 64 lanes x 16B = 1KB, frag-major):
//   qf_ws[b][strip32][ni2][kc4][lane]         8MB  (PRE-SCALED by log2e)
//   kt   [b][tile128][mb8][kc4][lane]         8MB
//   vt   [b][tile128][cb*16+wq][l16]{8}       8MB

typedef __bf16 v8bf __attribute__((ext_vector_type(8)));
typedef float  v4f  __attribute__((ext_vector_type(4)));

#define B_ 8
#define C_ 128
#define N_ 4096

// Swizzled LDS offset (in shorts) for the 128x160 proj tiles: row*160 plus the
// 16B-chunk index XOR'd with row bits 2..5. Bijective within the 16 data
// chunks per row; keeps 8-short chunks contiguous (b64/b128-safe).
#define SWZ(R, COLS) ((R) * 160 + (((((COLS) >> 3) ^ (((R) >> 2) & 15))) << 3) + ((COLS) & 7))

static __device__ __forceinline__ unsigned short f2bf_rne(float f) {
    union { float f; unsigned u; } v; v.f = f;
    return (unsigned short)((v.u + 0x7fffu + ((v.u >> 16) & 1u)) >> 16);
}
static __device__ __forceinline__ unsigned fbits(float f) {
    union { float f; unsigned u; } v; v.f = f; return v.u;
}

// ---------------------------------------------------------------------------
// Kernel 1: q/k/v projections. R9: swizzled 160-stride LDS tiles.
// ---------------------------------------------------------------------------
__global__ __launch_bounds__(256, 2) void proj_kernel(
    const float* __restrict__ x,
    const float* __restrict__ dw_q, const float* __restrict__ pw_q,
    const float* __restrict__ dw_k, const float* __restrict__ pw_k,
    const float* __restrict__ dw_v, const float* __restrict__ pw_v,
    unsigned short* __restrict__ qf_ws, unsigned short* __restrict__ kt,
    unsigned short* __restrict__ vt)
{
    __shared__ unsigned short xT[128 * 160];  // xT[n][c], swizzled
    __shared__ unsigned short Ws[128 * 160];  // W[o][c], swizzled; reused as store scratch

    const int bid = blockIdx.x;
    const int bb  = bid & 7;
    const int t   = (bid >> 3) & 31;
    const int pp  = bid >> 8;            // 0:q 1:k 2:v
    const int n0  = t * 128;
    const int tid = threadIdx.x;
    const int w    = tid >> 6;
    const int lane = tid & 63;
    const int quad = lane >> 4;
    const int l16  = lane & 15;

    #pragma unroll
    for (int k = 0; k < 16; ++k) {
        const int idx = tid + k * 256;
        const int c  = idx >> 5;
        const int nq = idx & 31;
        float4 f = *(const float4*)(x + ((size_t)(bb * C_ + c)) * N_ + n0 + nq * 4);
        xT[SWZ(nq * 4 + 0, c)] = f2bf_rne(f.x);
        xT[SWZ(nq * 4 + 1, c)] = f2bf_rne(f.y);
        xT[SWZ(nq * 4 + 2, c)] = f2bf_rne(f.z);
        xT[SWZ(nq * 4 + 3, c)] = f2bf_rne(f.w);
    }
    const float* pw = (pp == 0) ? pw_q : (pp == 1) ? pw_k : pw_v;
    const float* dw = (pp == 0) ? dw_q : (pp == 1) ? dw_k : dw_v;
    // log2(e) folded into Q weights: attn uses bare exp2.
    const float qs = (pp == 0) ? 1.4426950408889634f : 1.0f;
    #pragma unroll
    for (int k = 0; k < 16; ++k) {
        const int idx = tid + k * 256;
        const int o  = idx >> 5;
        const int c4 = (idx & 31) * 4;
        float4 p4 = *(const float4*)(pw + o * 128 + c4);
        float4 d4 = *(const float4*)(dw + c4);
        unsigned lo = (unsigned)f2bf_rne(p4.x * d4.x * qs) | ((unsigned)f2bf_rne(p4.y * d4.y * qs) << 16);
        unsigned hi = (unsigned)f2bf_rne(p4.z * d4.z * qs) | ((unsigned)f2bf_rne(p4.w * d4.w * qs) << 16);
        *(unsigned long long*)&Ws[SWZ(o, c4)] =
            (unsigned long long)lo | ((unsigned long long)hi << 32);
    }
    __syncthreads();

    const unsigned short* As = (pp < 2) ? xT : Ws;
    const unsigned short* Bs = (pp < 2) ? Ws : xT;

    v4f acc[2][8];
    #pragma unroll
    for (int i = 0; i < 2; ++i)
        #pragma unroll
        for (int j = 0; j < 8; ++j)
            acc[i][j] = (v4f){0.f, 0.f, 0.f, 0.f};

    #pragma unroll
    for (int kc = 0; kc < 4; ++kc) {
        v8bf av[2];
        #pragma unroll
        for (int i = 0; i < 2; ++i)
            av[i] = *(const v8bf*)&As[SWZ(w * 32 + i * 16 + l16, kc * 32 + quad * 8)];
        #pragma unroll
        for (int cb = 0; cb < 8; ++cb) {
            v8bf bv = *(const v8bf*)&Bs[SWZ(cb * 16 + l16, kc * 32 + quad * 8)];
            acc[0][cb] = __builtin_amdgcn_mfma_f32_16x16x32_bf16(av[0], bv, acc[0][cb], 0, 0, 0);
            acc[1][cb] = __builtin_amdgcn_mfma_f32_16x16x32_bf16(av[1], bv, acc[1][cb], 0, 0, 0);
        }
    }
    __syncthreads();

    unsigned short* sc = Ws;
    #pragma unroll
    for (int mi = 0; mi < 2; ++mi)
        #pragma unroll
        for (int cb = 0; cb < 8; ++cb)
            #pragma unroll
            for (int r = 0; r < 4; ++r)
                sc[SWZ(w * 32 + mi * 16 + quad * 4 + r, cb * 16 + l16)] =
                    f2bf_rne(acc[mi][cb][r]);
    __syncthreads();

    if (pp == 0) {
        unsigned short* dst = qf_ws + ((size_t)(bb * 64 + t * 2)) * 8192;
        #pragma unroll
        for (int p = 0; p < 8; ++p) {
            const int g     = p * 4 + w;
            const int strip = g >> 4, ni = (g >> 2) & 3, kc = g & 3;
            *(uint4*)(dst + ((size_t)g * 64 + lane) * 8) =
                *(const uint4*)&sc[SWZ(strip * 64 + ni * 16 + l16, kc * 32 + quad * 8)];
        }
    } else if (pp == 1) {
        unsigned short* dst = kt + ((size_t)(bb * 32 + t)) * 16384;
        #pragma unroll
        for (int p = 0; p < 8; ++p) {
            const int g  = p * 4 + w;
            const int mb = g >> 2, kc = g & 3;
            *(uint4*)(dst + ((size_t)g * 64 + lane) * 8) =
                *(const uint4*)&sc[SWZ(mb * 16 + l16, kc * 32 + quad * 8)];
        }
    } else {
        unsigned short* dst = vt + ((size_t)(bb * 32 + t)) * 16384;
        #pragma unroll
        for (int p = 0; p < 8; ++p) {
            const int d  = p * 256 + tid;
            const int cb = d >> 8, wq = (d >> 4) & 15, l = d & 15;
            *(uint4*)(dst + (size_t)d * 8) =
                *(const uint4*)&sc[SWZ(cb * 16 + l, wq * 8)];
        }
    }
}

// ---------------------------------------------------------------------------
// Kernel 2: attention (R7 structure verbatim -- best measured: 96.7us).
// grid 1024 = (b = bid&7, 32-row n-strip = bid>>3). 256 thr / 4 waves;
// wave = m-quarter, full c=128, n=32. Dual-sacc pipeline: softmax(t)
// interleaved with S-MFMAs of t+1; K register ping-pong; V single-buffer.
// ---------------------------------------------------------------------------
#define MFMA(A, B, C) __builtin_amdgcn_mfma_f32_16x16x32_bf16(A, B, C, 0, 0, 0)
#define EXP2(X) __builtin_amdgcn_exp2f(X)
#define PKPERM(EH, EL) __builtin_amdgcn_perm(fbits(EH), fbits(EL), 0x07060302)

#define LOADK(KF, TILE) { \
    const unsigned short* kp_ = kbase + (size_t)(TILE) * 16384; \
    _Pragma("unroll") \
    for (int mi_ = 0; mi_ < 2; ++mi_) \
        _Pragma("unroll") \
        for (int kc_ = 0; kc_ < 4; ++kc_) \
            KF[mi_][kc_] = *(const v8bf*)(kp_ + (size_t)((mi_ * 4 + kc_) * 64) * 8); \
}

#define LOADV(TILE) { \
    const unsigned short* vp_ = vbase + (size_t)(TILE) * 16384; \
    _Pragma("unroll") \
    for (int cb_ = 0; cb_ < 8; ++cb_) \
        vf[cb_] = *(const v8bf*)(vp_ + (size_t)(cb_ * 256) * 8); \
}

#define MKPF(NI, PK0A, PK0B, PK1A, PK1B) { \
    unsigned sLo_ = (quad < 2) ? PK0A : PK1A; \
    unsigned sHi_ = (quad < 2) ? PK0B : PK1B; \
    union { unsigned u[4]; v8bf v; } pu_; \
    pu_.u[0] = (unsigned)__builtin_amdgcn_ds_bpermute(la, (int)sLo_); \
    pu_.u[1] = (unsigned)__builtin_amdgcn_ds_bpermute(la, (int)sHi_); \
    pu_.u[2] = (unsigned)__builtin_amdgcn_ds_bpermute(lb, (int)sLo_); \
    pu_.u[3] = (unsigned)__builtin_amdgcn_ds_bpermute(lb, (int)sHi_); \
    pf[NI] = pu_.v; \
}

#define SCOMP0(KF, SC) { \
    _Pragma("unroll") \
    for (int mi_ = 0; mi_ < 2; ++mi_) \
        _Pragma("unroll") \
        for (int ni_ = 0; ni_ < 2; ++ni_) { \
            v4f a_ = MFMA(KF[mi_][0], qf[ni_][0], Z4v); \
            _Pragma("unroll") \
            for (int kc_ = 1; kc_ < 4; ++kc_) \
                a_ = MFMA(KF[mi_][kc_], qf[ni_][kc_], a_); \
            SC[mi_][ni_] = a_; \
        } \
}

// softmax(SC_IN) hand-interleaved with the 16 S-MFMAs of the next tile.
#define FUSED(SC_IN, KF, SC_OUT) { \
    float e0_, e1_, e2_, e3_; \
    unsigned pk00a_, pk00b_, pk10a_, pk10b_, pk01a_, pk01b_, pk11a_, pk11b_; \
    SC_OUT[0][0] = MFMA(KF[0][0], qf[0][0], Z4v); \
    SC_OUT[0][1] = MFMA(KF[0][0], qf[1][0], Z4v); \
    e0_ = EXP2(SC_IN[0][0][0]); e1_ = EXP2(SC_IN[0][0][1]); \
    e2_ = EXP2(SC_IN[0][0][2]); e3_ = EXP2(SC_IN[0][0][3]); \
    SC_OUT[0][0] = MFMA(KF[0][1], qf[0][1], SC_OUT[0][0]); \
    SC_OUT[0][1] = MFMA(KF[0][1], qf[1][1], SC_OUT[0][1]); \
    lpart[0] += (e0_ + e1_) + (e2_ + e3_); \
    pk00a_ = PKPERM(e1_, e0_); pk00b_ = PKPERM(e3_, e2_); \
    SC_OUT[0][0] = MFMA(KF[0][2], qf[0][2], SC_OUT[0][0]); \
    SC_OUT[0][1] = MFMA(KF[0][2], qf[1][2], SC_OUT[0][1]); \
    e0_ = EXP2(SC_IN[1][0][0]); e1_ = EXP2(SC_IN[1][0][1]); \
    e2_ = EXP2(SC_IN[1][0][2]); e3_ = EXP2(SC_IN[1][0][3]); \
    SC_OUT[0][0] = MFMA(KF[0][3], qf[0][3], SC_OUT[0][0]); \
    SC_OUT[0][1] = MFMA(KF[0][3], qf[1][3], SC_OUT[0][1]); \
    lpart[0] += (e0_ + e1_) + (e2_ + e3_); \
    pk10a_ = PKPERM(e1_, e0_); pk10b_ = PKPERM(e3_, e2_); \
    SC_OUT[1][0] = MFMA(KF[1][0], qf[0][0], Z4v); \
    SC_OUT[1][1] = MFMA(KF[1][0], qf[1][0], Z4v); \
    MKPF(0, pk00a_, pk00b_, pk10a_, pk10b_) \
    SC_OUT[1][0] = MFMA(KF[1][1], qf[0][1], SC_OUT[1][0]); \
    SC_OUT[1][1] = MFMA(KF[1][1], qf[1][1], SC_OUT[1][1]); \
    e0_ = EXP2(SC_IN[0][1][0]); e1_ = EXP2(SC_IN[0][1][1]); \
    e2_ = EXP2(SC_IN[0][1][2]); e3_ = EXP2(SC_IN[0][1][3]); \
    SC_OUT[1][0] = MFMA(KF[1][2], qf[0][2], SC_OUT[1][0]); \
    SC_OUT[1][1] = MFMA(KF[1][2], qf[1][2], SC_OUT[1][1]); \
    lpart[1] += (e0_ + e1_) + (e2_ + e3_); \
    pk01a_ = PKPERM(e1_, e0_); pk01b_ = PKPERM(e3_, e2_); \
    SC_OUT[1][0] = MFMA(KF[1][3], qf[0][3], SC_OUT[1][0]); \
    SC_OUT[1][1] = MFMA(KF[1][3], qf[1][3], SC_OUT[1][1]); \
    e0_ = EXP2(SC_IN[1][1][0]); e1_ = EXP2(SC_IN[1][1][1]); \
    e2_ = EXP2(SC_IN[1][1][2]); e3_ = EXP2(SC_IN[1][1][3]); \
    lpart[1] += (e0_ + e1_) + (e2_ + e3_); \
    pk11a_ = PKPERM(e1_, e0_); pk11b_ = PKPERM(e3_, e2_); \
    MKPF(1, pk01a_, pk01b_, pk11a_, pk11b_) \
}

#define PVOP { \
    _Pragma("unroll") \
    for (int ni_ = 0; ni_ < 2; ++ni_) \
        _Pragma("unroll") \
        for (int cb_ = 0; cb_ < 8; ++cb_) \
            oacc[cb_][ni_] = MFMA(vf[cb_], pf[ni_], oacc[cb_][ni_]); \
}

__global__ __launch_bounds__(256, 2) void attn_kernel(
    const unsigned short* __restrict__ qf_ws, const unsigned short* __restrict__ kt,
    const unsigned short* __restrict__ vt, const float* __restrict__ x,
    const float* __restrict__ gamma, float* __restrict__ out)
{
    __shared__ float red[32 * 132];   // O reduction scratch [n][c] (+pad)
    __shared__ float l_s[4][32];

    const int bid = blockIdx.x;
    const int bb  = bid & 7;
    const int s   = bid >> 3;        // n-strip 0..127 (32 rows each)
    const int n0  = s * 32;
    const int tid = threadIdx.x;
    const int w    = tid >> 6;       // wave = m-quarter owner
    const int lane = tid & 63;
    const int quad = lane >> 4;
    const int l16  = lane & 15;

    // ---- Q fragments (n=32 strip): 32 VGPR, iteration-invariant
    v8bf qf[2][4];
    {
        const unsigned short* qb = qf_ws + ((size_t)(bb * 128 + s)) * 4096;
        #pragma unroll
        for (int ni = 0; ni < 2; ++ni)
            #pragma unroll
            for (int kc = 0; kc < 4; ++kc)
                qf[ni][kc] = *(const v8bf*)(qb + ((size_t)(ni * 4 + kc) * 64 + lane) * 8);
    }

    v4f oacc[8][2];  // 64 regs: [cb][ni] partial O over this wave's 32-m subset
    #pragma unroll
    for (int i = 0; i < 8; ++i)
        #pragma unroll
        for (int j = 0; j < 2; ++j)
            oacc[i][j] = (v4f){0.f, 0.f, 0.f, 0.f};
    float lpart[2] = {0.f, 0.f};
    const v4f Z4v = {0.f, 0.f, 0.f, 0.f};

    const int la = ((((quad & 1) << 1) << 4) + l16) << 2;  // bpermute byte idx
    const int lb = la + 64;

    const unsigned short* kbase = kt + ((size_t)(bb * 32)) * 16384 + ((size_t)(w * 8) * 64 + lane) * 8;
    const unsigned short* vbase = vt + ((size_t)(bb * 32)) * 16384 + ((size_t)(w * 64 + lane)) * 8;

    v8bf kfA[2][4], kfB[2][4], vf[8];
    v4f sc0[2][2], sc1[2][2];
    v8bf pf[2];

    LOADK(kfA, 0)
    LOADV(0)
    LOADK(kfB, 1)
    SCOMP0(kfA, sc0)                 // S(0)

    for (int it = 0; it < 32; it += 2) {
        LOADK(kfA, (it + 2) & 31)    // K(t+2) in flight across this half-step
        FUSED(sc0, kfB, sc1)         // softmax(t) || S(t+1)
        PVOP                          // PV(t), consumes vf = V(t)
        LOADV((it + 1) & 31)
        LOADK(kfB, (it + 3) & 31)
        FUSED(sc1, kfA, sc0)         // softmax(t+1) || S(t+2)
        PVOP                          // PV(t+1)
        LOADV((it + 2) & 31)
    }

    // ---- softmax denominators (per-wave partials over its 32-m subset)
    #pragma unroll
    for (int ni = 0; ni < 2; ++ni) {
        float r = lpart[ni];
        r += __shfl_xor(r, 16);
        r += __shfl_xor(r, 32);
        if (lane < 16) l_s[w][ni * 16 + lane] = r;
    }

    // ---- O reduction across the 4 m-quarter waves
    for (int rw = 0; rw < 4; ++rw) {
        if (w == rw) {
            #pragma unroll
            for (int cb = 0; cb < 8; ++cb)
                #pragma unroll
                for (int ni = 0; ni < 2; ++ni) {
                    float* p = &red[(ni * 16 + l16) * 132 + cb * 16 + quad * 4];
                    if (rw == 0) *(v4f*)p = oacc[cb][ni];
                    else {
                        v4f tv = *(const v4f*)p;
                        tv += oacc[cb][ni];
                        *(v4f*)p = tv;
                    }
                }
        }
        __syncthreads();
    }

    // ---- epilogue: out = gamma * O / l + x  (thread: n = tid&31, c-group = tid>>5)
    const float g = gamma[0];
    const int   n = tid & 31;
    const int  cg = tid >> 5;        // 0..7
    const float li = 1.0f / (((l_s[0][n] + l_s[1][n]) + (l_s[2][n] + l_s[3][n])));
    #pragma unroll
    for (int j = 0; j < 16; ++j) {
        const int c = cg * 16 + j;
        const size_t idx = ((size_t)(bb * C_ + c)) * N_ + n0 + n;
        out[idx] = g * red[n * 132 + c] * li + x[idx];
    }
}

// ---------------------------------------------------------------------------
extern "C" void kernel_launch(void* const* d_in, const int* in_sizes, int n_in,
                              void* d_out, int out_size, void* d_ws, size_t ws_size,
                              hipStream_t stream)
{
    (void)in_sizes; (void)n_in; (void)out_size; (void)ws_size;
    const float* x     = (const float*)d_in[0];
    const float* dw_q  = (const float*)d_in[1];
    const float* pw_q  = (const float*)d_in[2];
    const float* dw_k  = (const float*)d_in[3];
    const float* pw_k  = (const float*)d_in[4];
    const float* dw_v  = (const float*)d_in[5];
    const float* pw_v  = (const float*)d_in[6];
    const float* gamma = (const float*)d_in[7];
    float* out = (float*)d_out;

    unsigned short* qf_ws = (unsigned short*)d_ws;                  // 8 MB
    unsigned short* kt    = qf_ws + (size_t)B_ * N_ * C_;           // 8 MB
    unsigned short* vt    = kt    + (size_t)B_ * N_ * C_;           // 8 MB

    proj_kernel<<<dim3(768), dim3(256), 0, stream>>>(
        x, dw_q, pw_q, dw_k, pw_k, dw_v, pw_v, qf_ws, kt, vt);
    attn_kernel<<<dim3(1024), dim3(256), 0, stream>>>(
        qf_ws, kt, vt, x, gamma, out);
}